// Round 1
// baseline (4471.586 us; speedup 1.0000x reference)
//
#include <hip/hip_runtime.h>
#include <math.h>

// Problem constants (from setup_inputs): faces (13776,3) int32, vertices (2,6890,3) f32, G=32.
#define GRD 32
#define P (GRD*GRD*GRD)      // 32768 points per mesh
#define NP (2*P)             // 65536 total points
#define NV 6890
#define NF 13776
#define NSPLIT 8
#define FC ((NF + NSPLIT - 1) / NSPLIT)   // 1722 triangles per split
#define TILE 256

__device__ __forceinline__ float safef(float x) {
    // reference _safe: |x|>1e-12 ? x : (x>=0 ? 1e-12 : -1e-12)
    float tiny = (x >= 0.0f) ? 1e-12f : -1e-12f;
    return fabsf(x) > 1e-12f ? x : tiny;
}

__global__ __launch_bounds__(256) void sdf_partial_kernel(
    const int* __restrict__ faces,
    const float* __restrict__ verts,
    float* __restrict__ dmin_part,
    double* __restrict__ wind_part)
{
    __shared__ float4 tri[TILE * 3];

    const int tid = threadIdx.x;
    const int s   = blockIdx.x & (NSPLIT - 1);
    const int pb  = blockIdx.x >> 3;          // NSPLIT == 8
    const int gp  = pb * 256 + tid;           // [0, NP)
    const int m   = gp >> 15;                 // mesh index (P == 32768)
    const int pid = gp & (P - 1);

    const int ix = pid >> 10;
    const int iy = (pid >> 5) & 31;
    const int iz = pid & 31;
    // (i + 0.5) * (2/32) - 1
    const float px = ix * 0.0625f - 0.96875f;
    const float py = iy * 0.0625f - 0.96875f;
    const float pz = iz * 0.0625f - 0.96875f;

    const float* __restrict__ vm = verts + m * (NV * 3);

    const int f0 = s * FC;
    const int f1 = (f0 + FC < NF) ? (f0 + FC) : NF;

    float dmin = 3.4e38f;
    double wind = 0.0;

    for (int base = f0; base < f1; base += TILE) {
        const int nt = (f1 - base < TILE) ? (f1 - base) : TILE;
        __syncthreads();
        if (tid < nt) {
            const int f  = base + tid;
            const int i0 = faces[3*f+0];
            const int i1 = faces[3*f+1];
            const int i2 = faces[3*f+2];
            const float ax = vm[3*i0+0], ay = vm[3*i0+1], az = vm[3*i0+2];
            const float bx = vm[3*i1+0], by = vm[3*i1+1], bz = vm[3*i1+2];
            const float cx = vm[3*i2+0], cy = vm[3*i2+1], cz = vm[3*i2+2];
            tri[3*tid+0] = make_float4(ax, ay, az, bx);
            tri[3*tid+1] = make_float4(by, bz, cx, cy);
            tri[3*tid+2] = make_float4(cz, 0.0f, 0.0f, 0.0f);
        }
        __syncthreads();

        for (int t = 0; t < nt; ++t) {
            const float4 t0 = tri[3*t+0];
            const float4 t1 = tri[3*t+1];
            const float4 t2 = tri[3*t+2];
            const float ax = t0.x, ay = t0.y, az = t0.z;
            const float bx = t0.w, by = t1.x, bz = t1.y;
            const float cx = t1.z, cy = t1.w, cz = t2.x;

            // ---------- point-triangle squared distance ----------
            const float abx = bx - ax, aby = by - ay, abz = bz - az;
            const float acx = cx - ax, acy = cy - ay, acz = cz - az;
            const float apx = px - ax, apy = py - ay, apz = pz - az;
            const float bpx = px - bx, bpy = py - by, bpz = pz - bz;
            const float cpx = px - cx, cpy = py - cy, cpz = pz - cz;

            const float d1 = fmaf(abx, apx, fmaf(aby, apy, abz * apz));
            const float d2 = fmaf(acx, apx, fmaf(acy, apy, acz * apz));
            const float d3 = fmaf(abx, bpx, fmaf(aby, bpy, abz * bpz));
            const float d4 = fmaf(acx, bpx, fmaf(acy, bpy, acz * bpz));
            const float d5 = fmaf(abx, cpx, fmaf(aby, cpy, abz * cpz));
            const float d6 = fmaf(acx, cpx, fmaf(acy, cpy, acz * cpz));

            const float vc = d1 * d4 - d3 * d2;
            const float vb = d5 * d2 - d1 * d6;
            const float va = d3 * d6 - d5 * d4;

            // interior (lowest priority)
            const float rden = __builtin_amdgcn_rcpf(safef(va + vb + vc));
            const float v_in = vb * rden;
            const float w_in = vc * rden;
            float qx = fmaf(w_in, acx, fmaf(v_in, abx, ax));
            float qy = fmaf(w_in, acy, fmaf(v_in, aby, ay));
            float qz = fmaf(w_in, acz, fmaf(v_in, abz, az));

            // edge bc
            const float e1 = d4 - d3, e2 = d5 - d6;
            const float t_bc = e1 * __builtin_amdgcn_rcpf(safef(e1 + e2));
            const bool on_bc = (va <= 0.0f) & (e1 >= 0.0f) & (e2 >= 0.0f);
            qx = on_bc ? fmaf(t_bc, cx - bx, bx) : qx;
            qy = on_bc ? fmaf(t_bc, cy - by, by) : qy;
            qz = on_bc ? fmaf(t_bc, cz - bz, bz) : qz;

            // edge ac
            const float t_ac = d2 * __builtin_amdgcn_rcpf(safef(d2 - d6));
            const bool on_ac = (vb <= 0.0f) & (d2 >= 0.0f) & (d6 <= 0.0f);
            qx = on_ac ? fmaf(t_ac, acx, ax) : qx;
            qy = on_ac ? fmaf(t_ac, acy, ay) : qy;
            qz = on_ac ? fmaf(t_ac, acz, az) : qz;

            // edge ab
            const float t_ab = d1 * __builtin_amdgcn_rcpf(safef(d1 - d3));
            const bool on_ab = (vc <= 0.0f) & (d1 >= 0.0f) & (d3 <= 0.0f);
            qx = on_ab ? fmaf(t_ab, abx, ax) : qx;
            qy = on_ab ? fmaf(t_ab, aby, ay) : qy;
            qz = on_ab ? fmaf(t_ab, abz, az) : qz;

            // vertex regions (highest priority last)
            const bool in_c = (d6 >= 0.0f) & (d5 <= d6);
            qx = in_c ? cx : qx;  qy = in_c ? cy : qy;  qz = in_c ? cz : qz;
            const bool in_b = (d3 >= 0.0f) & (d4 <= d3);
            qx = in_b ? bx : qx;  qy = in_b ? by : qy;  qz = in_b ? bz : qz;
            const bool in_a = (d1 <= 0.0f) & (d2 <= 0.0f);
            qx = in_a ? ax : qx;  qy = in_a ? ay : qy;  qz = in_a ? az : qz;

            const float dxx = px - qx, dyy = py - qy, dzz = pz - qz;
            const float dsq = fmaf(dxx, dxx, fmaf(dyy, dyy, dzz * dzz));
            dmin = fminf(dmin, dsq);

            // ---------- solid angle ----------
            // va3 = a-p = -ap, vb3 = -bp, vc3 = -cp.
            // norms/dots are negation-invariant; triple product flips sign.
            const float la = __builtin_amdgcn_sqrtf(fmaf(apx, apx, fmaf(apy, apy, apz * apz)));
            const float lb = __builtin_amdgcn_sqrtf(fmaf(bpx, bpx, fmaf(bpy, bpy, bpz * bpz)));
            const float lc = __builtin_amdgcn_sqrtf(fmaf(cpx, cpx, fmaf(cpy, cpy, cpz * cpz)));

            const float crx = bpy * cpz - bpz * cpy;
            const float cry = bpz * cpx - bpx * cpz;
            const float crz = bpx * cpy - bpy * cpx;
            float num = -(fmaf(apx, crx, fmaf(apy, cry, apz * crz)));

            const float dab = fmaf(apx, bpx, fmaf(apy, bpy, apz * bpz));
            const float dbc = fmaf(bpx, cpx, fmaf(bpy, cpy, bpz * cpz));
            const float dca = fmaf(cpx, apx, fmaf(cpy, apy, cpz * apz));
            const float den = fmaf(la * lb, lc, fmaf(dab, lc, fmaf(dbc, la, dca * lb)));

            // atan2 branch-cut guard: if num is within fp32 noise of 0, its sign
            // (and hence an ~±2π flip of omega when den<0) is unreliable ->
            // recompute the triple product in fp64. Rare, so predication is cheap.
            if (fabsf(num) < 1e-4f * (la * lb) * lc) {
                const double ax_ = apx, ay_ = apy, az_ = apz;
                const double bx_ = bpx, by_ = bpy, bz_ = bpz;
                const double cx_ = cpx, cy_ = cpy, cz_ = cpz;
                const double nd = -(ax_ * (by_ * cz_ - bz_ * cy_)
                                  + ay_ * (bz_ * cx_ - bx_ * cz_)
                                  + az_ * (bx_ * cy_ - by_ * cx_));
                num = (float)nd;
            }

            const float omega = 2.0f * atan2f(num, den);
            wind += (double)omega;
        }
    }

    dmin_part[s * NP + gp] = dmin;
    wind_part[s * NP + gp] = wind;
}

__global__ __launch_bounds__(256) void sdf_final_kernel(
    const float* __restrict__ dmin_part,
    const double* __restrict__ wind_part,
    float* __restrict__ out)
{
    const int g = blockIdx.x * 256 + threadIdx.x;   // [0, NP)
    float dmin = 3.4e38f;
    double wind = 0.0;
#pragma unroll
    for (int s = 0; s < NSPLIT; ++s) {
        dmin = fminf(dmin, dmin_part[s * NP + g]);
        wind += wind_part[s * NP + g];
    }
    const float dist = __builtin_amdgcn_sqrtf(dmin + 1e-12f);
    out[g] = (wind > 6.283185307179586) ? dist : 0.0f;
}

extern "C" void kernel_launch(void* const* d_in, const int* in_sizes, int n_in,
                              void* d_out, int out_size, void* d_ws, size_t ws_size,
                              hipStream_t stream) {
    const int*   faces = (const int*)d_in[0];
    const float* verts = (const float*)d_in[1];
    float*       out   = (float*)d_out;

    // workspace layout: [ dmin_part: NSPLIT*NP f32 = 2 MB ][ wind_part: NSPLIT*NP f64 = 4 MB ]
    float*  dmin_part = (float*)d_ws;
    double* wind_part = (double*)((char*)d_ws + (size_t)NSPLIT * NP * sizeof(float));

    sdf_partial_kernel<<<dim3((NP / 256) * NSPLIT), dim3(256), 0, stream>>>(
        faces, verts, dmin_part, wind_part);
    sdf_final_kernel<<<dim3(NP / 256), dim3(256), 0, stream>>>(
        dmin_part, wind_part, out);
}

// Round 2
// 2993.590 us; speedup vs baseline: 1.4937x; 1.4937x over previous
//
#include <hip/hip_runtime.h>
#include <math.h>

// Problem constants: faces (13776,3) int32, vertices (2,6890,3) f32, G=32.
#define GRD 32
#define P (GRD*GRD*GRD)      // 32768 points per mesh
#define NP (2*P)             // 65536 total points
#define NV 6890
#define NF 13776
#define NSPLIT 8
#define FC ((NF + NSPLIT - 1) / NSPLIT)   // 1722 triangles per split (exact: 8*1722=13776)
#define TILE 256

__device__ __forceinline__ float safef(float x) {
    // reference _safe: |x|>1e-12 ? x : (x>=0 ? 1e-12 : -1e-12)
    float tiny = (x >= 0.0f) ? 1e-12f : -1e-12f;
    return fabsf(x) > 1e-12f ? x : tiny;
}

// fast atan2: range-reduce to [0,1] via min/max, half-angle to [0,0.4142],
// Cephes 4-term poly. Max err ~5e-7 rad. No NaN/Inf handling (inputs finite;
// mx clamped so (0,0) -> 0).
__device__ __forceinline__ float atan2_fast(float y, float x) {
    const float ay = fabsf(y), ax = fabsf(x);
    const float mn = fminf(ay, ax);
    float       mx = fmaxf(ay, ax);
    mx = fmaxf(mx, 1e-37f);
    const float r = mn * __builtin_amdgcn_rcpf(mx);          // [0,1]
    // atan(r) = 2*atan(r / (1 + sqrt(1+r^2))), arg in [0, tan(pi/8)]
    const float s = fmaf(r, r, 1.0f);
    const float q = __builtin_amdgcn_sqrtf(s);
    const float u = r * __builtin_amdgcn_rcpf(1.0f + q);
    const float z = u * u;
    float p = fmaf(8.05374449538e-2f, z, -1.38776856032e-1f);
    p = fmaf(p, z, 1.99777106478e-1f);
    p = fmaf(p, z, -3.33329491539e-1f);
    float a = 2.0f * fmaf(p * z, u, u);                      // atan(r), [0, pi/4]
    a = (ay > ax) ? (1.57079632679489662f - a) : a;
    a = (x < 0.0f) ? (3.14159265358979323f - a) : a;
    return copysignf(a, y);
}

// Per-triangle precompute: 16 floats per (mesh,face):
// [ax ay az | abx aby abz | acx acy acz | Cabab Cabac Cacac | Nx Ny Nz | pad]
__global__ __launch_bounds__(256) void sdf_prep_kernel(
    const int* __restrict__ faces,
    const float* __restrict__ verts,
    float4* __restrict__ pre4)
{
    const int idx = blockIdx.x * 256 + threadIdx.x;   // [0, 2*NF)
    if (idx >= 2 * NF) return;
    const int m = idx >= NF ? 1 : 0;
    const int f = idx - m * NF;
    const float* __restrict__ vm = verts + m * (NV * 3);
    const int i0 = faces[3*f+0], i1 = faces[3*f+1], i2 = faces[3*f+2];
    const float ax = vm[3*i0+0], ay = vm[3*i0+1], az = vm[3*i0+2];
    const float bx = vm[3*i1+0], by = vm[3*i1+1], bz = vm[3*i1+2];
    const float cx = vm[3*i2+0], cy = vm[3*i2+1], cz = vm[3*i2+2];
    const float abx = bx - ax, aby = by - ay, abz = bz - az;
    const float acx = cx - ax, acy = cy - ay, acz = cz - az;
    const float Cabab = fmaf(abx, abx, fmaf(aby, aby, abz * abz));
    const float Cabac = fmaf(abx, acx, fmaf(aby, acy, abz * acz));
    const float Cacac = fmaf(acx, acx, fmaf(acy, acy, acz * acz));
    const float Nx = aby * acz - abz * acy;
    const float Ny = abz * acx - abx * acz;
    const float Nz = abx * acy - aby * acx;
    pre4[4*idx+0] = make_float4(ax, ay, az, abx);
    pre4[4*idx+1] = make_float4(aby, abz, acx, acy);
    pre4[4*idx+2] = make_float4(acz, Cabab, Cabac, Cacac);
    pre4[4*idx+3] = make_float4(Nx, Ny, Nz, 0.0f);
}

__global__ __launch_bounds__(256) void sdf_partial_kernel(
    const float4* __restrict__ pre4,
    float* __restrict__ dmin_part,
    double* __restrict__ wind_part)
{
    __shared__ float4 tri[TILE * 4];

    const int tid = threadIdx.x;
    const int s   = blockIdx.x & (NSPLIT - 1);
    const int pb  = blockIdx.x >> 3;          // NSPLIT == 8
    const int gp  = pb * 256 + tid;           // [0, NP)
    const int m   = gp >> 15;                 // mesh index (P == 32768)
    const int pid = gp & (P - 1);

    const int ix = pid >> 10;
    const int iy = (pid >> 5) & 31;
    const int iz = pid & 31;
    const float px = ix * 0.0625f - 0.96875f;
    const float py = iy * 0.0625f - 0.96875f;
    const float pz = iz * 0.0625f - 0.96875f;

    const int f0 = s * FC;
    const int f1 = f0 + FC;                    // exact split
    const float4* __restrict__ base4 = pre4 + (size_t)4 * (m * NF);

    float dmin = 3.4e38f;
    double wind = 0.0;

    for (int base = f0; base < f1; base += TILE) {
        const int nt = (f1 - base < TILE) ? (f1 - base) : TILE;
        __syncthreads();
        if (tid < nt) {
            const float4* __restrict__ src = base4 + (size_t)4 * (base + tid);
            tri[4*tid+0] = src[0];
            tri[4*tid+1] = src[1];
            tri[4*tid+2] = src[2];
            tri[4*tid+3] = src[3];
        }
        __syncthreads();

        for (int t = 0; t < nt; ++t) {
            const float4 q0 = tri[4*t+0];
            const float4 q1 = tri[4*t+1];
            const float4 q2 = tri[4*t+2];
            const float4 q3 = tri[4*t+3];
            const float ax = q0.x,  ay = q0.y,  az = q0.z;
            const float abx = q0.w, aby = q1.x, abz = q1.y;
            const float acx = q1.z, acy = q1.w, acz = q2.x;
            const float Cabab = q2.y, Cabac = q2.z, Cacac = q2.w;

            const float apx = px - ax, apy = py - ay, apz = pz - az;

            const float d1 = fmaf(abx, apx, fmaf(aby, apy, abz * apz));
            const float d2 = fmaf(acx, apx, fmaf(acy, apy, acz * apz));
            const float d3 = d1 - Cabab;   // dot(ab, bp)
            const float d4 = d2 - Cabac;   // dot(ac, bp)
            const float d5 = d1 - Cabac;   // dot(ab, cp)
            const float d6 = d2 - Cacac;   // dot(ac, cp)
            const float papap = fmaf(apx, apx, fmaf(apy, apy, apz * apz));

            const float vc = d1 * d4 - d3 * d2;
            const float vb = d5 * d2 - d1 * d6;
            const float va = d3 * d6 - d5 * d4;
            const float e1 = d4 - d3, e2 = d5 - d6;

            // region predicates (reference override order: interior < bc < ac < ab < c < b < a)
            const bool on_bc = (va <= 0.0f) & (e1 >= 0.0f) & (e2 >= 0.0f);
            const bool on_ac = (vb <= 0.0f) & (d2 >= 0.0f) & (d6 <= 0.0f);
            const bool on_ab = (vc <= 0.0f) & (d1 >= 0.0f) & (d3 <= 0.0f);
            const bool in_c  = (d6 >= 0.0f) & (e2 <= 0.0f);   // d5 <= d6
            const bool in_b  = (d3 >= 0.0f) & (e1 <= 0.0f);   // d4 <= d3
            const bool in_a  = (d1 <= 0.0f) & (d2 <= 0.0f);

            // single edge-parameter division
            float tn = 0.0f, td = 1.0f;
            tn = on_bc ? e1 : tn;  td = on_bc ? (e1 + e2) : td;   // |bc|^2
            tn = on_ac ? d2 : tn;  td = on_ac ? Cacac : td;
            tn = on_ab ? d1 : tn;  td = on_ab ? Cabab : td;
            const float t_e = tn * __builtin_amdgcn_rcpf(safef(td));

            // interior barycentric division
            const float rden = __builtin_amdgcn_rcpf(safef(va + vb + vc));
            float alpha = vb * rden;
            float beta  = vc * rden;

            // q = a + alpha*ab + beta*ac for every region
            alpha = on_bc ? (1.0f - t_e) : alpha;  beta = on_bc ? t_e : beta;
            alpha = on_ac ? 0.0f : alpha;          beta = on_ac ? t_e : beta;
            alpha = on_ab ? t_e : alpha;           beta = on_ab ? 0.0f : beta;
            alpha = in_c ? 0.0f : alpha;           beta = in_c ? 1.0f : beta;
            alpha = in_b ? 1.0f : alpha;           beta = in_b ? 0.0f : beta;
            alpha = in_a ? 0.0f : alpha;           beta = in_a ? 0.0f : beta;

            const float qx = fmaf(beta, acx, fmaf(alpha, abx, ax));
            const float qy = fmaf(beta, acy, fmaf(alpha, aby, ay));
            const float qz = fmaf(beta, acz, fmaf(alpha, abz, az));
            const float dxx = px - qx, dyy = py - qy, dzz = pz - qz;
            const float dsq = fmaf(dxx, dxx, fmaf(dyy, dyy, dzz * dzz));
            dmin = fminf(dmin, dsq);

            // ---------- solid angle (identities; bp/cp never formed) ----------
            const float pbpb = fmaf(-2.0f, d1, papap) + Cabab;   // |bp|^2
            const float pcpc = fmaf(-2.0f, d2, papap) + Cacac;   // |cp|^2
            const float la = __builtin_amdgcn_sqrtf(papap);
            const float lb = __builtin_amdgcn_sqrtf(pbpb);
            const float lc = __builtin_amdgcn_sqrtf(pcpc);
            const float dab = papap - d1;      // dot(ap,bp)
            const float dca = papap - d2;      // dot(cp,ap)
            const float dbc = dab - d4;        // dot(bp,cp)

            // num = dot(a-p, cross(b-p,c-p)) = -dot(ap, N), N = cross(ab,ac)
            float num = -fmaf(apx, q3.x, fmaf(apy, q3.y, apz * q3.z));
            const float lalb = la * lb;
            const float den = fmaf(lalb, lc, fmaf(dab, lc, fmaf(dbc, la, dca * lb)));

            // branch-cut guard: tiny |num| -> fp64 recompute for a reliable sign
            if (fabsf(num) < 1e-4f * (lalb * lc)) {
                const double Apx = apx, Apy = apy, Apz = apz;
                const double Bpx = Apx - (double)abx, Bpy = Apy - (double)aby, Bpz = Apz - (double)abz;
                const double Cpx = Apx - (double)acx, Cpy = Apy - (double)acy, Cpz = Apz - (double)acz;
                const double nd = -(Apx * (Bpy * Cpz - Bpz * Cpy)
                                  + Apy * (Bpz * Cpx - Bpx * Cpz)
                                  + Apz * (Bpx * Cpy - Bpy * Cpx));
                num = (float)nd;
            }

            const float omega = 2.0f * atan2_fast(num, den);
            wind += (double)omega;
        }
    }

    dmin_part[s * NP + gp] = dmin;
    wind_part[s * NP + gp] = wind;
}

__global__ __launch_bounds__(256) void sdf_final_kernel(
    const float* __restrict__ dmin_part,
    const double* __restrict__ wind_part,
    float* __restrict__ out)
{
    const int g = blockIdx.x * 256 + threadIdx.x;   // [0, NP)
    float dmin = 3.4e38f;
    double wind = 0.0;
#pragma unroll
    for (int s = 0; s < NSPLIT; ++s) {
        dmin = fminf(dmin, dmin_part[s * NP + g]);
        wind += wind_part[s * NP + g];
    }
    const float dist = __builtin_amdgcn_sqrtf(dmin + 1e-12f);
    out[g] = (wind > 6.283185307179586) ? dist : 0.0f;
}

extern "C" void kernel_launch(void* const* d_in, const int* in_sizes, int n_in,
                              void* d_out, int out_size, void* d_ws, size_t ws_size,
                              hipStream_t stream) {
    const int*   faces = (const int*)d_in[0];
    const float* verts = (const float*)d_in[1];
    float*       out   = (float*)d_out;

    // ws layout: [dmin_part: 8*65536 f32 = 2MB][wind_part: 8*65536 f64 = 4MB][pre: 2*13776*16 f32 = 1.76MB]
    float*  dmin_part = (float*)d_ws;
    double* wind_part = (double*)((char*)d_ws + (size_t)NSPLIT * NP * sizeof(float));
    float4* pre4      = (float4*)((char*)wind_part + (size_t)NSPLIT * NP * sizeof(double));

    sdf_prep_kernel<<<dim3((2 * NF + 255) / 256), dim3(256), 0, stream>>>(faces, verts, pre4);
    sdf_partial_kernel<<<dim3((NP / 256) * NSPLIT), dim3(256), 0, stream>>>(pre4, dmin_part, wind_part);
    sdf_final_kernel<<<dim3(NP / 256), dim3(256), 0, stream>>>(dmin_part, wind_part, out);
}

// Round 3
// 2663.513 us; speedup vs baseline: 1.6788x; 1.1239x over previous
//
#include <hip/hip_runtime.h>
#include <math.h>

// Problem constants: faces (13776,3) int32, vertices (2,6890,3) f32, G=32.
#define GRD 32
#define P (GRD*GRD*GRD)      // 32768 points per mesh
#define NP (2*P)             // 65536 total points
#define NV 6890
#define NF 13776
#define NSPLIT 8
#define FC (NF / NSPLIT)     // 1722 exactly (8*1722 = 13776)

__device__ __forceinline__ float safef(float x) {
    // reference _safe: |x|>1e-12 ? x : (x>=0 ? 1e-12 : -1e-12)
    float tiny = (x >= 0.0f) ? 1e-12f : -1e-12f;
    return fabsf(x) > 1e-12f ? x : tiny;
}

// Per-triangle precompute, 5 float4 (80 B) per (mesh,face):
// q0 = (ax,ay,az, |ab|^2)  q1 = (abx,aby,abz, ab.ac)  q2 = (acx,acy,acz, |ac|^2)
// q3 = (Nx,Ny,Nz, 1/safe|ab|^2)  q4 = (1/safe|ac|^2, 1/safe|bc|^2, 0, 0)
__global__ __launch_bounds__(256) void sdf_prep_kernel(
    const int* __restrict__ faces,
    const float* __restrict__ verts,
    float4* __restrict__ pre)
{
    const int idx = blockIdx.x * 256 + threadIdx.x;   // [0, 2*NF)
    if (idx >= 2 * NF) return;
    const int m = idx >= NF ? 1 : 0;
    const int f = idx - m * NF;
    const float* __restrict__ vm = verts + m * (NV * 3);
    const int i0 = faces[3*f+0], i1 = faces[3*f+1], i2 = faces[3*f+2];
    const float ax = vm[3*i0+0], ay = vm[3*i0+1], az = vm[3*i0+2];
    const float bx = vm[3*i1+0], by = vm[3*i1+1], bz = vm[3*i1+2];
    const float cx = vm[3*i2+0], cy = vm[3*i2+1], cz = vm[3*i2+2];
    const float abx = bx - ax, aby = by - ay, abz = bz - az;
    const float acx = cx - ax, acy = cy - ay, acz = cz - az;
    const float bcx = cx - bx, bcy = cy - by, bcz = cz - bz;
    const float A = fmaf(abx, abx, fmaf(aby, aby, abz * abz));   // |ab|^2
    const float B = fmaf(abx, acx, fmaf(aby, acy, abz * acz));   // ab.ac
    const float C = fmaf(acx, acx, fmaf(acy, acy, acz * acz));   // |ac|^2
    const float Cbc = fmaf(bcx, bcx, fmaf(bcy, bcy, bcz * bcz)); // |bc|^2
    const float Nx = aby * acz - abz * acy;
    const float Ny = abz * acx - abx * acz;
    const float Nz = abx * acy - aby * acx;
    pre[5*idx+0] = make_float4(ax, ay, az, A);
    pre[5*idx+1] = make_float4(abx, aby, abz, B);
    pre[5*idx+2] = make_float4(acx, acy, acz, C);
    pre[5*idx+3] = make_float4(Nx, Ny, Nz, 1.0f / safef(A));
    pre[5*idx+4] = make_float4(1.0f / safef(C), 1.0f / safef(Cbc), 0.0f, 0.0f);
}

__global__ __launch_bounds__(256) void sdf_partial_kernel(
    const float4* __restrict__ pre,
    float* __restrict__ dmin_part,
    double* __restrict__ wind_part)
{
    const int tid = threadIdx.x;
    const int s   = blockIdx.x & (NSPLIT - 1);
    const int pb  = blockIdx.x >> 3;          // NSPLIT == 8
    const int gp  = pb * 256 + tid;           // [0, NP)
    const int m   = gp >> 15;                 // mesh index (P == 32768)
    const int pid = gp & (P - 1);

    const int ix = pid >> 10;
    const int iy = (pid >> 5) & 31;
    const int iz = pid & 31;
    const float px = ix * 0.0625f - 0.96875f;
    const float py = iy * 0.0625f - 0.96875f;
    const float pz = iz * 0.0625f - 0.96875f;

    // wave-uniform triangle stream -> scalar (s_load) path, no LDS
    const float4* __restrict__ tp = pre + (size_t)5 * (m * NF + s * FC);

    float dmin = 3.4e38f;
    double wind = 0.0;

    for (int cc = 0; cc < FC; cc += 64) {
        const int ce = (cc + 64 < FC) ? (cc + 64) : FC;
        float wf = 0.0f;                      // f32 chunk accumulator for phi
        for (int k = cc; k < ce; ++k) {
            const float4 q0 = tp[5*k+0];
            const float4 q1 = tp[5*k+1];
            const float4 q2 = tp[5*k+2];
            const float4 q3 = tp[5*k+3];
            const float4 q4 = tp[5*k+4];
            const float ax = q0.x, ayy = q0.y, az = q0.z, A = q0.w;
            const float abx = q1.x, aby = q1.y, abz = q1.z, B = q1.w;
            const float acx = q2.x, acy = q2.y, acz = q2.z, C = q2.w;

            const float apx = px - ax, apy = py - ayy, apz = pz - az;
            const float papap = fmaf(apx, apx, fmaf(apy, apy, apz * apz));
            const float d1 = fmaf(abx, apx, fmaf(aby, apy, abz * apz));
            const float d2 = fmaf(acx, apx, fmaf(acy, apy, acz * apz));
            const float d3 = d1 - A;   // dot(ab,bp)
            const float d4 = d2 - B;   // dot(ac,bp)
            const float d5 = d1 - B;   // dot(ab,cp)
            const float d6 = d2 - C;   // dot(ac,cp)

            const float vc = fmaf(d1, d4, -(d3 * d2));
            const float vb = fmaf(d5, d2, -(d1 * d6));
            const float va = fmaf(d3, d6, -(d5 * d4));
            const float e1 = d4 - d3, e2 = d5 - d6;

            // region predicates (reference override order: interior<bc<ac<ab<c<b<a)
            const bool on_bc = (va <= 0.0f) & (e1 >= 0.0f) & (e2 >= 0.0f);
            const bool on_ac = (vb <= 0.0f) & (d2 >= 0.0f) & (d6 <= 0.0f);
            const bool on_ab = (vc <= 0.0f) & (d1 >= 0.0f) & (d3 <= 0.0f);
            const bool in_c  = (d6 >= 0.0f) & (e2 <= 0.0f);
            const bool in_b  = (d3 >= 0.0f) & (e1 <= 0.0f);
            const bool in_a  = (d1 <= 0.0f) & (d2 <= 0.0f);

            // edge parameter: numerator select x precomputed reciprocal (no rcp)
            float tn = on_ac ? d2 : e1;     tn = on_ab ? d1 : tn;
            float rE = on_ac ? q4.x : q4.y; rE = on_ab ? q3.w : rE;
            const float t_e = tn * rE;

            // interior barycentric (the single per-pair rcp)
            const float ssum = (va + vb) + vc;
            const float rden = __builtin_amdgcn_rcpf(safef(ssum));
            float alpha = vb * rden;
            float beta  = vc * rden;

            alpha = on_bc ? (1.0f - t_e) : alpha;  beta = (on_bc | on_ac) ? t_e : beta;
            alpha = on_ac ? 0.0f : alpha;
            alpha = on_ab ? t_e  : alpha;          beta = on_ab ? 0.0f : beta;
            alpha = in_c  ? 0.0f : alpha;          beta = in_c  ? 1.0f : beta;
            alpha = in_b  ? 1.0f : alpha;          beta = (in_b | in_a) ? 0.0f : beta;
            alpha = in_a  ? 0.0f : alpha;

            const float cqx = fmaf(beta, acx, fmaf(alpha, abx, ax));
            const float cqy = fmaf(beta, acy, fmaf(alpha, aby, ayy));
            const float cqz = fmaf(beta, acz, fmaf(alpha, abz, az));
            const float dx = px - cqx, dy = py - cqy, dz = pz - cqz;
            const float dsq = fmaf(dx, dx, fmaf(dy, dy, dz * dz));
            dmin = fminf(dmin, dsq);

            // ---------- solid angle (identities; bp/cp never formed) ----------
            const float pbpb = fmaf(-2.0f, d1, papap) + A;
            const float pcpc = fmaf(-2.0f, d2, papap) + C;
            const float la = __builtin_amdgcn_sqrtf(papap);
            const float lb = __builtin_amdgcn_sqrtf(pbpb);
            const float lc = __builtin_amdgcn_sqrtf(pcpc);
            const float dab = papap - d1;
            const float dca = papap - d2;
            const float dbc = dab - d4;
            // num = dot(a-p, cross(b-p,c-p)) = -dot(ap, N)
            const float num = -fmaf(apx, q3.x, fmaf(apy, q3.y, apz * q3.z));
            const float den = fmaf(la * lb, lc, fmaf(dab, lc, fmaf(dbc, la, dca * lb)));

            // phi = atan2(num, den) = omega/2 ; single-rcp half-angle form
            const float aay = fabsf(num), aax = fabsf(den);
            const float mn = fminf(aay, aax);
            const float mx = fmaxf(aay, aax);
            const float hyp2 = fmaf(num, num, den * den);
            const float L = __builtin_amdgcn_sqrtf(hyp2);
            const float dd = fmaxf(mx + L, 1e-37f);
            const float u = mn * __builtin_amdgcn_rcpf(dd);   // = tan(atan(mn/mx)/2)
            const float z = u * u;
            float pl = fmaf(1.610748899076e-1f, z, -2.775537120640e-1f);  // 2x Cephes
            pl = fmaf(pl, z, 3.995542129560e-1f);
            pl = fmaf(pl, z, -6.666589830780e-1f);
            float at2 = fmaf(pl * z, u, u + u);               // = atan(mn/mx)
            at2 = (aay > aax) ? (1.57079632679489662f - at2) : at2;
            at2 = (den < 0.0f) ? (3.14159265358979323f - at2) : at2;
            wf += copysignf(at2, num);
        }
        wind += (double)wf;
    }

    dmin_part[s * NP + gp] = dmin;
    wind_part[s * NP + gp] = wind;
}

__global__ __launch_bounds__(256) void sdf_final_kernel(
    const float* __restrict__ dmin_part,
    const double* __restrict__ wind_part,
    float* __restrict__ out)
{
    const int g = blockIdx.x * 256 + threadIdx.x;   // [0, NP)
    float dmin = 3.4e38f;
    double wind = 0.0;
#pragma unroll
    for (int s = 0; s < NSPLIT; ++s) {
        dmin = fminf(dmin, dmin_part[s * NP + g]);
        wind += wind_part[s * NP + g];
    }
    const float dist = __builtin_amdgcn_sqrtf(dmin + 1e-12f);
    // accumulated phi = omega/2, so inside test is sum(phi) > pi
    out[g] = (wind > 3.14159265358979323846) ? dist : 0.0f;
}

extern "C" void kernel_launch(void* const* d_in, const int* in_sizes, int n_in,
                              void* d_out, int out_size, void* d_ws, size_t ws_size,
                              hipStream_t stream) {
    const int*   faces = (const int*)d_in[0];
    const float* verts = (const float*)d_in[1];
    float*       out   = (float*)d_out;

    // ws: [dmin_part 8*65536 f32 = 2MB][wind_part 8*65536 f64 = 4MB][pre 2*13776*80B = 2.2MB]
    float*  dmin_part = (float*)d_ws;
    double* wind_part = (double*)((char*)d_ws + (size_t)NSPLIT * NP * sizeof(float));
    float4* pre       = (float4*)((char*)wind_part + (size_t)NSPLIT * NP * sizeof(double));

    sdf_prep_kernel<<<dim3((2 * NF + 255) / 256), dim3(256), 0, stream>>>(faces, verts, pre);
    sdf_partial_kernel<<<dim3((NP / 256) * NSPLIT), dim3(256), 0, stream>>>(pre, dmin_part, wind_part);
    sdf_final_kernel<<<dim3(NP / 256), dim3(256), 0, stream>>>(dmin_part, wind_part, out);
}

// Round 8
// 2649.619 us; speedup vs baseline: 1.6876x; 1.0052x over previous
//
#include <hip/hip_runtime.h>
#include <math.h>

// Problem constants: faces (13776,3) int32, vertices (2,6890,3) f32, G=32.
#define GRD 32
#define P (GRD*GRD*GRD)      // 32768 points per mesh
#define NP (2*P)             // 65536 total points
#define NV 6890
#define NF 13776
#define NSPLIT 8
#define FC (NF / NSPLIT)     // 1722 exactly (even -> unroll-by-2 safe)

__device__ __forceinline__ float safef(float x) {
    // reference _safe: |x|>1e-12 ? x : (x>=0 ? 1e-12 : -1e-12)
    float tiny = (x >= 0.0f) ? 1e-12f : -1e-12f;
    return fabsf(x) > 1e-12f ? x : tiny;
}

// precise-enough atan2 (err ~5e-7 rad), used only 8x per point in the final kernel
__device__ __forceinline__ float atan2_fast(float y, float x) {
    const float ay = fabsf(y), ax = fabsf(x);
    const float mn = fminf(ay, ax);
    const float mx = fmaxf(fmaxf(ay, ax), 1e-37f);
    const float hyp2 = fmaf(y, y, x * x);
    const float L = __builtin_amdgcn_sqrtf(hyp2);
    const float u = mn * __builtin_amdgcn_rcpf(fmaxf(mx + L, 1e-37f)); // tan(theta/2)
    const float z = u * u;
    float pl = fmaf(1.610748899076e-1f, z, -2.775537120640e-1f);
    pl = fmaf(pl, z, 3.995542129560e-1f);
    pl = fmaf(pl, z, -6.666589830780e-1f);
    float a = fmaf(pl * z, u, u + u);                 // atan(mn/mx)
    a = (ay > ax) ? (1.57079632679489662f - a) : a;
    a = (x < 0.0f) ? (3.14159265358979323f - a) : a;
    return copysignf(a, y);
}

// Per-triangle precompute, 5 float4 (80 B) — EXACT R3 layout/values:
// q0 = (a, A)  q1 = (ab, B)  q2 = (ac, C)
// q3 = (N, 1/safe(A))  q4 = (1/safe(C), 1/safe(Cbc), 0, 0)
__global__ __launch_bounds__(256) void sdf_prep_kernel(
    const int* __restrict__ faces,
    const float* __restrict__ verts,
    float4* __restrict__ pre)
{
    const int idx = blockIdx.x * 256 + threadIdx.x;   // [0, 2*NF)
    if (idx >= 2 * NF) return;
    const int m = idx >= NF ? 1 : 0;
    const int f = idx - m * NF;
    const float* __restrict__ vm = verts + m * (NV * 3);
    const int i0 = faces[3*f+0], i1 = faces[3*f+1], i2 = faces[3*f+2];
    const float ax = vm[3*i0+0], ay = vm[3*i0+1], az = vm[3*i0+2];
    const float bx = vm[3*i1+0], by = vm[3*i1+1], bz = vm[3*i1+2];
    const float cx = vm[3*i2+0], cy = vm[3*i2+1], cz = vm[3*i2+2];
    const float abx = bx - ax, aby = by - ay, abz = bz - az;
    const float acx = cx - ax, acy = cy - ay, acz = cz - az;
    const float bcx = cx - bx, bcy = cy - by, bcz = cz - bz;
    const float A   = fmaf(abx, abx, fmaf(aby, aby, abz * abz));
    const float B   = fmaf(abx, acx, fmaf(aby, acy, abz * acz));
    const float C   = fmaf(acx, acx, fmaf(acy, acy, acz * acz));
    const float Cbc = fmaf(bcx, bcx, fmaf(bcy, bcy, bcz * bcz));
    const float Nx = aby * acz - abz * acy;
    const float Ny = abz * acx - abx * acz;
    const float Nz = abx * acy - aby * acx;
    pre[5*idx+0] = make_float4(ax, ay, az, A);
    pre[5*idx+1] = make_float4(abx, aby, abz, B);
    pre[5*idx+2] = make_float4(acx, acy, acz, C);
    pre[5*idx+3] = make_float4(Nx, Ny, Nz, 1.0f / safef(A));
    pre[5*idx+4] = make_float4(1.0f / safef(C), 1.0f / safef(Cbc), 0.0f, 0.0f);
}

__global__ __launch_bounds__(256) void sdf_partial_kernel(
    const float4* __restrict__ pre,
    float* __restrict__ dmin_part,
    float2* __restrict__ zri_part,
    int* __restrict__ wnum_part)
{
    const int tid = threadIdx.x;
    const int s   = blockIdx.x & (NSPLIT - 1);
    const int pb  = blockIdx.x >> 3;
    const int gp  = pb * 256 + tid;           // [0, NP)
    const int m   = gp >> 15;
    const int pid = gp & (P - 1);

    const int ix = pid >> 10;
    const int iy = (pid >> 5) & 31;
    const int iz = pid & 31;
    const float px = ix * 0.0625f - 0.96875f;
    const float py = iy * 0.0625f - 0.96875f;
    const float pz = iz * 0.0625f - 0.96875f;

    // wave-uniform triangle stream (scalar loads)
    const float4* __restrict__ tp = pre + (size_t)5 * (m * NF + s * FC);

    float dmin = 3.4e38f;
    // winding as complex product: z accumulates angle mod 2pi, W counts wraps
    float zr = 1.0f, zi = 0.0f;
    int W = 0;

    auto body = [&](int k) {
        const float4 q0 = tp[5*k+0];
        const float4 q1 = tp[5*k+1];
        const float4 q2 = tp[5*k+2];
        const float4 q3 = tp[5*k+3];
        const float4 q4 = tp[5*k+4];
        const float ax = q0.x, ayy = q0.y, az = q0.z, A = q0.w;
        const float abx = q1.x, aby = q1.y, abz = q1.z, B = q1.w;
        const float acx = q2.x, acy = q2.y, acz = q2.z, C = q2.w;

        const float apx = px - ax, apy = py - ayy, apz = pz - az;
        const float papap = fmaf(apx, apx, fmaf(apy, apy, apz * apz));
        const float d1 = fmaf(abx, apx, fmaf(aby, apy, abz * apz));
        const float d2 = fmaf(acx, apx, fmaf(acy, apy, acz * apz));
        const float d3 = d1 - A;   // dot(ab,bp)
        const float d4 = d2 - B;   // dot(ac,bp)
        const float d5 = d1 - B;   // dot(ab,cp)
        const float d6 = d2 - C;   // dot(ac,cp)

        const float vc = fmaf(d1, d4, -(d3 * d2));
        const float vb = fmaf(d5, d2, -(d1 * d6));
        const float va = fmaf(d3, d6, -(d5 * d4));
        const float e1 = d4 - d3, e2 = d5 - d6;

        // ---------- distance: EXACT R3 construction (reference override chain,
        // incl. the barycentric fall-through that produces the UNCLAMPED plane
        // projection when no predicate fires — must not be "improved": sliver
        // triangles rely on reproducing that quirk) ----------
        const bool on_bc = (va <= 0.0f) & (e1 >= 0.0f) & (e2 >= 0.0f);
        const bool on_ac = (vb <= 0.0f) & (d2 >= 0.0f) & (d6 <= 0.0f);
        const bool on_ab = (vc <= 0.0f) & (d1 >= 0.0f) & (d3 <= 0.0f);
        const bool in_c  = (d6 >= 0.0f) & (e2 <= 0.0f);
        const bool in_b  = (d3 >= 0.0f) & (e1 <= 0.0f);
        const bool in_a  = (d1 <= 0.0f) & (d2 <= 0.0f);

        float tn = on_ac ? d2 : e1;     tn = on_ab ? d1 : tn;
        float rE = on_ac ? q4.x : q4.y; rE = on_ab ? q3.w : rE;
        const float t_e = tn * rE;

        const float ssum = (va + vb) + vc;
        const float rden = __builtin_amdgcn_rcpf(safef(ssum));
        float alpha = vb * rden;
        float beta  = vc * rden;

        alpha = on_bc ? (1.0f - t_e) : alpha;  beta = (on_bc | on_ac) ? t_e : beta;
        alpha = on_ac ? 0.0f : alpha;
        alpha = on_ab ? t_e  : alpha;          beta = on_ab ? 0.0f : beta;
        alpha = in_c  ? 0.0f : alpha;          beta = in_c  ? 1.0f : beta;
        alpha = in_b  ? 1.0f : alpha;          beta = (in_b | in_a) ? 0.0f : beta;
        alpha = in_a  ? 0.0f : alpha;

        const float cqx = fmaf(beta, acx, fmaf(alpha, abx, ax));
        const float cqy = fmaf(beta, acy, fmaf(alpha, aby, ayy));
        const float cqz = fmaf(beta, acz, fmaf(alpha, abz, az));
        const float dx = px - cqx, dy = py - cqy, dz = pz - cqz;
        const float dsq = fmaf(dx, dx, fmaf(dy, dy, dz * dz));
        dmin = fminf(dmin, dsq);

        // ---------- winding: num/den bit-identical to R3 (identity-based) ----------
        const float pbpb = fmaf(-2.0f, d1, papap) + A;
        const float pcpc = fmaf(-2.0f, d2, papap) + C;
        const float la = __builtin_amdgcn_sqrtf(papap);
        const float lb = __builtin_amdgcn_sqrtf(pbpb);
        const float lc = __builtin_amdgcn_sqrtf(pcpc);
        const float dab = papap - d1;
        const float dca = papap - d2;
        const float dbc = dab - d4;
        const float num = -fmaf(apx, q3.x, fmaf(apy, q3.y, apz * q3.z));
        const float den = fmaf(la * lb, lc, fmaf(dab, lc, fmaf(dbc, la, dca * lb)));

        // z *= (du, num). (0,0) (incl. signed zeros) -> (1,0): phi=0, matching
        // R3's atan2_fast((+-0),(+-0))=+-0 behavior. For num=+-0, den<0 the
        // rotation is exactly +-pi, also matching R3/atan2 convention.
        float du = den;
        if ((num == 0.0f) & (den == 0.0f)) du = 1.0f;

        const bool npos   = !__builtin_signbitf(num);  // sign of phi incl. +-0
        const bool zo_pos = (zi >= 0.0f);
        const float zr_n = fmaf(zr, du, -(zi * num));
        const float zi_n = fmaf(zr, num, zi * du);
        const bool zn_neg = (zi_n < 0.0f);
        // CCW through -x axis: +2pi ; CW through -x axis: -2pi
        W += (npos & zo_pos & zn_neg) ? 1 : 0;
        W -= ((!npos) & (!zo_pos) & (!zn_neg)) ? 1 : 0;
        zr = zr_n; zi = zi_n;
    };

    for (int k = 0; k < FC; k += 2) {
        body(k);
        body(k + 1);
        // renormalize every 2 steps (positive scale: angle & wrap state invariant)
        const float h2 = fmaf(zr, zr, zi * zi);
        const float sc = __builtin_amdgcn_rsqf(fmaxf(h2, 1e-30f));
        zr *= sc; zi *= sc;
    }

    dmin_part[s * NP + gp] = dmin;
    zri_part[s * NP + gp]  = make_float2(zr, zi);
    wnum_part[s * NP + gp] = W;
}

__global__ __launch_bounds__(256) void sdf_final_kernel(
    const float* __restrict__ dmin_part,
    const float2* __restrict__ zri_part,
    const int* __restrict__ wnum_part,
    float* __restrict__ out)
{
    const int g = blockIdx.x * 256 + threadIdx.x;   // [0, NP)
    float dmin = 3.4e38f;
    double wind = 0.0;
#pragma unroll
    for (int s = 0; s < NSPLIT; ++s) {
        dmin = fminf(dmin, dmin_part[s * NP + g]);
        const float2 z = zri_part[s * NP + g];
        const int    w = wnum_part[s * NP + g];
        // per-split sum of phi = atan2 of product + 2pi * wraps (phi = omega/2)
        wind += 6.283185307179586 * (double)w + (double)atan2_fast(z.y, z.x);
    }
    const float dist = __builtin_amdgcn_sqrtf(dmin + 1e-12f);
    out[g] = (wind > 3.14159265358979323846) ? dist : 0.0f;   // sum(omega)/2 > pi
}

extern "C" void kernel_launch(void* const* d_in, const int* in_sizes, int n_in,
                              void* d_out, int out_size, void* d_ws, size_t ws_size,
                              hipStream_t stream) {
    const int*   faces = (const int*)d_in[0];
    const float* verts = (const float*)d_in[1];
    float*       out   = (float*)d_out;

    // ws: [dmin 2MB][zri 4MB][wnum 2MB][pre 2*13776*80B = 2.2MB]
    char* w = (char*)d_ws;
    float*  dmin_part = (float*)w;                                   w += (size_t)NSPLIT * NP * sizeof(float);
    float2* zri_part  = (float2*)w;                                  w += (size_t)NSPLIT * NP * sizeof(float2);
    int*    wnum_part = (int*)w;                                     w += (size_t)NSPLIT * NP * sizeof(int);
    float4* pre       = (float4*)w;

    sdf_prep_kernel<<<dim3((2 * NF + 255) / 256), dim3(256), 0, stream>>>(faces, verts, pre);
    sdf_partial_kernel<<<dim3((NP / 256) * NSPLIT), dim3(256), 0, stream>>>(pre, dmin_part, zri_part, wnum_part);
    sdf_final_kernel<<<dim3(NP / 256), dim3(256), 0, stream>>>(dmin_part, zri_part, wnum_part, out);
}

// Round 9
// 1888.246 us; speedup vs baseline: 2.3681x; 1.4032x over previous
//
#include <hip/hip_runtime.h>
#include <math.h>

// Problem constants: faces (13776,3) int32, vertices (2,6890,3) f32, G=32.
#define GRD 32
#define P (GRD*GRD*GRD)      // 32768 points per mesh
#define NP (2*P)             // 65536 total points
#define NV 6890
#define NF 13776
#define NSPLIT 8
#define FC (NF / NSPLIT)     // 1722 exactly (even -> unroll-by-2 safe)

__device__ __forceinline__ float safef(float x) {
    // reference _safe: |x|>1e-12 ? x : (x>=0 ? 1e-12 : -1e-12)
    float tiny = (x >= 0.0f) ? 1e-12f : -1e-12f;
    return fabsf(x) > 1e-12f ? x : tiny;
}

// precise-enough atan2 (err ~5e-7 rad), used only 8x per point in the final kernel
__device__ __forceinline__ float atan2_fast(float y, float x) {
    const float ay = fabsf(y), ax = fabsf(x);
    const float mn = fminf(ay, ax);
    const float mx = fmaxf(fmaxf(ay, ax), 1e-37f);
    const float hyp2 = fmaf(y, y, x * x);
    const float L = __builtin_amdgcn_sqrtf(hyp2);
    const float u = mn * __builtin_amdgcn_rcpf(fmaxf(mx + L, 1e-37f)); // tan(theta/2)
    const float z = u * u;
    float pl = fmaf(1.610748899076e-1f, z, -2.775537120640e-1f);
    pl = fmaf(pl, z, 3.995542129560e-1f);
    pl = fmaf(pl, z, -6.666589830780e-1f);
    float a = fmaf(pl * z, u, u + u);                 // atan(mn/mx)
    a = (ay > ax) ? (1.57079632679489662f - a) : a;
    a = (x < 0.0f) ? (3.14159265358979323f - a) : a;
    return copysignf(a, y);
}

// Per-triangle precompute, 5 float4 (80 B) — R3/R8 layout + rNN in q4.z:
// q0 = (a, A)  q1 = (ab, B)  q2 = (ac, C)
// q3 = (N, 1/safe(A))  q4 = (1/safe(C), 1/safe(Cbc), 1/safe(NN), 0)
__global__ __launch_bounds__(256) void sdf_prep_kernel(
    const int* __restrict__ faces,
    const float* __restrict__ verts,
    float4* __restrict__ pre)
{
    const int idx = blockIdx.x * 256 + threadIdx.x;   // [0, 2*NF)
    if (idx >= 2 * NF) return;
    const int m = idx >= NF ? 1 : 0;
    const int f = idx - m * NF;
    const float* __restrict__ vm = verts + m * (NV * 3);
    const int i0 = faces[3*f+0], i1 = faces[3*f+1], i2 = faces[3*f+2];
    const float ax = vm[3*i0+0], ay = vm[3*i0+1], az = vm[3*i0+2];
    const float bx = vm[3*i1+0], by = vm[3*i1+1], bz = vm[3*i1+2];
    const float cx = vm[3*i2+0], cy = vm[3*i2+1], cz = vm[3*i2+2];
    const float abx = bx - ax, aby = by - ay, abz = bz - az;
    const float acx = cx - ax, acy = cy - ay, acz = cz - az;
    const float bcx = cx - bx, bcy = cy - by, bcz = cz - bz;
    const float A   = fmaf(abx, abx, fmaf(aby, aby, abz * abz));
    const float B   = fmaf(abx, acx, fmaf(aby, acy, abz * acz));
    const float C   = fmaf(acx, acx, fmaf(acy, acy, acz * acz));
    const float Cbc = fmaf(bcx, bcx, fmaf(bcy, bcy, bcz * bcz));
    const float Nx = aby * acz - abz * acy;
    const float Ny = abz * acx - abx * acz;
    const float Nz = abx * acy - aby * acx;
    const float NN = fmaf(Nx, Nx, fmaf(Ny, Ny, Nz * Nz));
    pre[5*idx+0] = make_float4(ax, ay, az, A);
    pre[5*idx+1] = make_float4(abx, aby, abz, B);
    pre[5*idx+2] = make_float4(acx, acy, acz, C);
    pre[5*idx+3] = make_float4(Nx, Ny, Nz, 1.0f / safef(A));
    pre[5*idx+4] = make_float4(1.0f / safef(C), 1.0f / safef(Cbc), 1.0f / safef(NN), 0.0f);
}

__global__ __launch_bounds__(256) void sdf_partial_kernel(
    const float4* __restrict__ pre,
    float* __restrict__ dmin_part,
    float2* __restrict__ zri_part,
    int* __restrict__ wnum_part)
{
    const int tid = threadIdx.x;
    const int s   = blockIdx.x & (NSPLIT - 1);
    const int pb  = blockIdx.x >> 3;
    const int gp  = pb * 256 + tid;           // [0, NP)
    const int m   = gp >> 15;
    const int pid = gp & (P - 1);

    const int ix = pid >> 10;
    const int iy = (pid >> 5) & 31;
    const int iz = pid & 31;
    const float px = ix * 0.0625f - 0.96875f;
    const float py = iy * 0.0625f - 0.96875f;
    const float pz = iz * 0.0625f - 0.96875f;

    // wave-uniform triangle stream (scalar loads)
    const float4* __restrict__ tp = pre + (size_t)5 * (m * NF + s * FC);

    float dmin = 3.4e38f;
    // winding as complex product: z accumulates angle mod 2pi, W counts wraps
    float zr = 1.0f, zi = 0.0f;
    int W = 0;

    auto body = [&](int k) {
        const float4 q0 = tp[5*k+0];
        const float4 q1 = tp[5*k+1];
        const float4 q2 = tp[5*k+2];
        const float4 q3 = tp[5*k+3];
        const float4 q4 = tp[5*k+4];
        const float ax = q0.x, ayy = q0.y, az = q0.z, A = q0.w;
        const float abx = q1.x, aby = q1.y, abz = q1.z, B = q1.w;
        const float acx = q2.x, acy = q2.y, acz = q2.z, C = q2.w;

        const float apx = px - ax, apy = py - ayy, apz = pz - az;
        const float papap = fmaf(apx, apx, fmaf(apy, apy, apz * apz));
        const float d1 = fmaf(abx, apx, fmaf(aby, apy, abz * apz));
        const float d2 = fmaf(acx, apx, fmaf(acy, apy, acz * apz));
        const float d4 = d2 - B;   // dot(ac,bp): winding (dbc) + distance
        const float num = -fmaf(apx, q3.x, fmaf(apy, q3.y, apz * q3.z));

        // ---------- conservative screen ----------
        // Every q the reference constructs (incl. sliver fall-through garbage)
        // lies in the triangle plane => dsq_exact >= num^2/max(NN,1e-12) always
        // (clamped rNN only lowers the bound). If that bound already exceeds the
        // running dmin for ALL lanes, fminf can't change dmin -> skip the whole
        // region/select/q block. dmin stays bit-identical to the full version.
        const float plane2 = (num * num) * q4.z;
        const bool take = plane2 <= fmaf(dmin, 1.000001f, 1e-9f);
        if (__any(take)) {
            // ---------- distance: EXACT R8/R3 construction (reference override
            // chain incl. barycentric fall-through quirks — do not "improve") ----
            const float d3 = d1 - A;   // dot(ab,bp)
            const float d5 = d1 - B;   // dot(ab,cp)
            const float d6 = d2 - C;   // dot(ac,cp)

            const float vc = fmaf(d1, d4, -(d3 * d2));
            const float vb = fmaf(d5, d2, -(d1 * d6));
            const float va = fmaf(d3, d6, -(d5 * d4));
            const float e1 = d4 - d3, e2 = d5 - d6;

            const bool on_bc = (va <= 0.0f) & (e1 >= 0.0f) & (e2 >= 0.0f);
            const bool on_ac = (vb <= 0.0f) & (d2 >= 0.0f) & (d6 <= 0.0f);
            const bool on_ab = (vc <= 0.0f) & (d1 >= 0.0f) & (d3 <= 0.0f);
            const bool in_c  = (d6 >= 0.0f) & (e2 <= 0.0f);
            const bool in_b  = (d3 >= 0.0f) & (e1 <= 0.0f);
            const bool in_a  = (d1 <= 0.0f) & (d2 <= 0.0f);

            float tn = on_ac ? d2 : e1;     tn = on_ab ? d1 : tn;
            float rE = on_ac ? q4.x : q4.y; rE = on_ab ? q3.w : rE;
            const float t_e = tn * rE;

            const float ssum = (va + vb) + vc;
            const float rden = __builtin_amdgcn_rcpf(safef(ssum));
            float alpha = vb * rden;
            float beta  = vc * rden;

            alpha = on_bc ? (1.0f - t_e) : alpha;  beta = (on_bc | on_ac) ? t_e : beta;
            alpha = on_ac ? 0.0f : alpha;
            alpha = on_ab ? t_e  : alpha;          beta = on_ab ? 0.0f : beta;
            alpha = in_c  ? 0.0f : alpha;          beta = in_c  ? 1.0f : beta;
            alpha = in_b  ? 1.0f : alpha;          beta = (in_b | in_a) ? 0.0f : beta;
            alpha = in_a  ? 0.0f : alpha;

            const float cqx = fmaf(beta, acx, fmaf(alpha, abx, ax));
            const float cqy = fmaf(beta, acy, fmaf(alpha, aby, ayy));
            const float cqz = fmaf(beta, acz, fmaf(alpha, abz, az));
            const float dx = px - cqx, dy = py - cqy, dz = pz - cqz;
            const float dsq = fmaf(dx, dx, fmaf(dy, dy, dz * dz));
            dmin = fminf(dmin, dsq);
        }

        // ---------- winding: bit-identical to R8 (identity-based) ----------
        const float pbpb = fmaf(-2.0f, d1, papap) + A;
        const float pcpc = fmaf(-2.0f, d2, papap) + C;
        const float la = __builtin_amdgcn_sqrtf(papap);
        const float lb = __builtin_amdgcn_sqrtf(pbpb);
        const float lc = __builtin_amdgcn_sqrtf(pcpc);
        const float dab = papap - d1;
        const float dca = papap - d2;
        const float dbc = dab - d4;
        const float den = fmaf(la * lb, lc, fmaf(dab, lc, fmaf(dbc, la, dca * lb)));

        // z *= (du, num). (0,0) -> (1,0): phi=0; num=+-0, den<0 rotates by +-pi,
        // matching atan2 convention.
        float du = den;
        if ((num == 0.0f) & (den == 0.0f)) du = 1.0f;

        const bool npos   = !__builtin_signbitf(num);  // sign of phi incl. +-0
        const bool zo_pos = (zi >= 0.0f);
        const float zr_n = fmaf(zr, du, -(zi * num));
        const float zi_n = fmaf(zr, num, zi * du);
        const bool zn_neg = (zi_n < 0.0f);
        // CCW through -x axis: +2pi ; CW through -x axis: -2pi
        W += (npos & zo_pos & zn_neg) ? 1 : 0;
        W -= ((!npos) & (!zo_pos) & (!zn_neg)) ? 1 : 0;
        zr = zr_n; zi = zi_n;
    };

    for (int k = 0; k < FC; k += 2) {
        body(k);
        body(k + 1);
        // renormalize every 2 steps (positive scale: angle & wrap state invariant)
        const float h2 = fmaf(zr, zr, zi * zi);
        const float sc = __builtin_amdgcn_rsqf(fmaxf(h2, 1e-30f));
        zr *= sc; zi *= sc;
    }

    dmin_part[s * NP + gp] = dmin;
    zri_part[s * NP + gp]  = make_float2(zr, zi);
    wnum_part[s * NP + gp] = W;
}

__global__ __launch_bounds__(256) void sdf_final_kernel(
    const float* __restrict__ dmin_part,
    const float2* __restrict__ zri_part,
    const int* __restrict__ wnum_part,
    float* __restrict__ out)
{
    const int g = blockIdx.x * 256 + threadIdx.x;   // [0, NP)
    float dmin = 3.4e38f;
    double wind = 0.0;
#pragma unroll
    for (int s = 0; s < NSPLIT; ++s) {
        dmin = fminf(dmin, dmin_part[s * NP + g]);
        const float2 z = zri_part[s * NP + g];
        const int    w = wnum_part[s * NP + g];
        // per-split sum of phi = atan2 of product + 2pi * wraps (phi = omega/2)
        wind += 6.283185307179586 * (double)w + (double)atan2_fast(z.y, z.x);
    }
    const float dist = __builtin_amdgcn_sqrtf(dmin + 1e-12f);
    out[g] = (wind > 3.14159265358979323846) ? dist : 0.0f;   // sum(omega)/2 > pi
}

extern "C" void kernel_launch(void* const* d_in, const int* in_sizes, int n_in,
                              void* d_out, int out_size, void* d_ws, size_t ws_size,
                              hipStream_t stream) {
    const int*   faces = (const int*)d_in[0];
    const float* verts = (const float*)d_in[1];
    float*       out   = (float*)d_out;

    // ws: [dmin 2MB][zri 4MB][wnum 2MB][pre 2*13776*80B = 2.2MB]
    char* w = (char*)d_ws;
    float*  dmin_part = (float*)w;                                   w += (size_t)NSPLIT * NP * sizeof(float);
    float2* zri_part  = (float2*)w;                                  w += (size_t)NSPLIT * NP * sizeof(float2);
    int*    wnum_part = (int*)w;                                     w += (size_t)NSPLIT * NP * sizeof(int);
    float4* pre       = (float4*)w;

    sdf_prep_kernel<<<dim3((2 * NF + 255) / 256), dim3(256), 0, stream>>>(faces, verts, pre);
    sdf_partial_kernel<<<dim3((NP / 256) * NSPLIT), dim3(256), 0, stream>>>(pre, dmin_part, zri_part, wnum_part);
    sdf_final_kernel<<<dim3(NP / 256), dim3(256), 0, stream>>>(dmin_part, zri_part, wnum_part, out);
}